// Round 19
// baseline (22.115 us; speedup 1.0000x reference)
//
#include <hip/hip_runtime.h>

#define VOLD 256
// Region = 16(x) x 32(y) x 32(z); grid 16 x 8 x 8 = 1024 blocks, 1024 threads.
// LDS 44.5 KB + 16 waves/block -> exactly 2 blocks/CU resident (32-wave cap),
// so the 1024-block grid runs as TWO sequential batches: batch-1's NT-store
// drain overlaps batch-2's compute (scan+weights+K-loop ~7us > 5.25us drain).
#define CXD 16
#define CYD 32
#define CZD 32
#define NBLK 1024
#define CAP 128

typedef float nfloat4 __attribute__((ext_vector_type(4)));
typedef float f2 __attribute__((ext_vector_type(2)));

__global__ __launch_bounds__(1024) void splat_kernel(
    const float* __restrict__ centers, const float* __restrict__ sigmas,
    const float* __restrict__ intens, float* __restrict__ vol, int N)
{
    const int cell = blockIdx.x;
    const int czc = cell & 7;            // 0..7
    const int cyc = (cell >> 3) & 7;     // 0..7
    const int cxc = cell >> 6;           // 0..15
    const int vx0 = cxc * CXD, vy0 = cyc * CYD, vz0 = czc * CZD;
    const int t = threadIdx.x;

    __shared__ int           lcnt;
    __shared__ float4        pc4[CAP];        // cx, cy, cz, sigma
    __shared__ float         pint[CAP];       // intensity
    __shared__ float         wx[CAP][CXD];    // intensity folded in
    __shared__ float         wy[CAP][CYD];
    __shared__ float         wz[CAP][CZD];
    __shared__ unsigned char wlist[16][CAP];  // per-wave compacted k-lists
    // 44.5 KB; 16 waves/block -> 2 blocks/CU (wave cap), 512 resident of 1024

    if (t == 0) lcnt = 0;
    __syncthreads();

    // ---- Scan: 4-gaussian packs, 4 x dwordx4 loads per pack. ----
    const float axh = (float)(vx0 + CXD) + 0.5f, axl = (float)vx0 - 0.5f;
    const float ayh = (float)(vy0 + CYD) + 0.5f, ayl = (float)vy0 - 0.5f;
    const float azh = (float)(vz0 + CZD) + 0.5f, azl = (float)vz0 - 0.5f;

    const float4* c4 = (const float4*)centers;
    const float4* s4 = (const float4*)sigmas;
    const int npack = N >> 2;
    for (int i = t; i < npack; i += 1024) {
        const float4 f0  = c4[3 * i];
        const float4 f1  = c4[3 * i + 1];
        const float4 f2v = c4[3 * i + 2];
        const float4 sg4 = s4[i];
        const float gx[4] = {f0.x, f0.w, f1.z, f2v.y};
        const float gy[4] = {f0.y, f1.x, f1.w, f2v.z};
        const float gz[4] = {f0.z, f1.y, f2v.x, f2v.w};
        const float gs[4] = {sg4.x, sg4.y, sg4.z, sg4.w};
        #pragma unroll
        for (int u = 0; u < 4; ++u) {
            const float m1 = fmaxf(fmaxf(fmaf(gx[u], 255.0f, -axh),
                                         fmaf(gy[u], 255.0f, -ayh)),
                                         fmaf(gz[u], 255.0f, -azh));
            const float m2 = fmaxf(fmaxf(fmaf(-gx[u], 255.0f, axl),
                                         fmaf(-gy[u], 255.0f, ayl)),
                                         fmaf(-gz[u], 255.0f, azl));
            if (fmaxf(m1, m2) < gs[u] * 765.0f) {
                const int p = atomicAdd(&lcnt, 1);
                if (p < CAP) {
                    pc4[p]  = make_float4(gx[u], gy[u], gz[u], gs[u]);
                    pint[p] = intens[4 * i + u];
                }
            }
        }
    }
    for (int g = (npack << 2) + t; g < N; g += 1024) {   // tail, robustness
        const float cx = centers[3 * g], cy = centers[3 * g + 1], cz = centers[3 * g + 2];
        const float sg = sigmas[g];
        const float m1 = fmaxf(fmaxf(fmaf(cx, 255.0f, -axh), fmaf(cy, 255.0f, -ayh)),
                               fmaf(cz, 255.0f, -azh));
        const float m2 = fmaxf(fmaxf(fmaf(-cx, 255.0f, axl), fmaf(-cy, 255.0f, ayl)),
                               fmaf(-cz, 255.0f, azl));
        if (fmaxf(m1, m2) < sg * 765.0f) {
            const int p = atomicAdd(&lcnt, 1);
            if (p < CAP) { pc4[p] = make_float4(cx, cy, cz, sg); pint[p] = intens[g]; }
        }
    }
    __syncthreads();
    const int K = min(lcnt, CAP);

    // ---- Weights (float-domain validity == reference's floor/int logic). ----
    for (int i = t; i < K * CXD; i += 1024) {
        const int g = i >> 4, o = i & 15;
        const float4 p = pc4[g];
        const float cn = p.x, sig = p.w;
        const float cv = cn * 255.0f, cut = 3.0f * sig * 255.0f;
        const float fi = (float)(vx0 + o);
        float wv = 0.0f;
        if ((fi + 1.0f > cv - cut) && (fi <= fminf(cv + cut, 255.0f))) {
            const float d = fi * (1.0f / 255.0f) - cn;
            wv = __expf(-d * d * (0.5f / (sig * sig))) * pint[g];
        }
        wx[g][o] = wv;
    }
    for (int i = t; i < K * CYD; i += 1024) {
        const int g = i >> 5, o = i & 31;
        const float4 p = pc4[g];
        const float cn = p.y, sig = p.w;
        const float cv = cn * 255.0f, cut = 3.0f * sig * 255.0f;
        const float fi = (float)(vy0 + o);
        float wv = 0.0f;
        if ((fi + 1.0f > cv - cut) && (fi <= fminf(cv + cut, 255.0f))) {
            const float d = fi * (1.0f / 255.0f) - cn;
            wv = __expf(-d * d * (0.5f / (sig * sig)));
        }
        wy[g][o] = wv;
    }
    for (int i = t; i < K * CZD; i += 1024) {
        const int g = i >> 5, o = i & 31;
        const float4 p = pc4[g];
        const float cn = p.z, sig = p.w;
        const float cv = cn * 255.0f, cut = 3.0f * sig * 255.0f;
        const float fi = (float)(vz0 + o);
        float wv = 0.0f;
        if ((fi + 1.0f > cv - cut) && (fi <= fminf(cv + cut, 255.0f))) {
            const float d = fi * (1.0f / 255.0f) - cn;
            wv = __expf(-d * d * (0.5f / (sig * sig)));
        }
        wz[g][o] = wv;
    }
    __syncthreads();

    // ---- Per-wave list compaction: this wave's 8x x 4y footprint. ----
    const int wv_id = t >> 6;            // wave 0..15 (2x in x, 8x in y)
    const int lane  = t & 63;
    const float xw0 = (float)(vx0 + 8 * (wv_id & 1));   // x-window [xw0, xw0+8)
    const float yw0 = (float)(vy0 + 4 * (wv_id >> 1));  // y-window [yw0, yw0+4)

    int Kw = 0;
    for (int j0 = 0; j0 < K; j0 += 64) {
        const int j = j0 + lane;
        bool rel = false;
        if (j < K) {
            const float4 p = pc4[j];
            const float cvx = p.x * 255.0f, cvy = p.y * 255.0f;
            const float cut = p.w * 765.0f;
            // loose (+1 voxel) overlap vs weight support: false POSITIVES only
            rel = (cvx + cut >= xw0 - 1.0f) && (cvx - cut <= xw0 + 9.0f) &&
                  (cvy + cut >= yw0 - 1.0f) && (cvy - cut <= yw0 + 5.0f);
        }
        const unsigned long long m = __ballot(rel);
        if (rel) {
            const int pos = Kw + __popcll(m & ((1ull << lane) - 1ull));
            wlist[wv_id][pos] = (unsigned char)j;
        }
        Kw += __popcll(m);
    }
    // wlist[wv_id] written & read by the same wave only -> no barrier needed.

    // ---- Accumulate over compacted list: simple body, TLP hides LDS latency. -
    const int zq = t & 7;                              // z = 4*zq .. 4*zq+3
    const int xi = 8 * (wv_id & 1) + ((t >> 3) & 7);   // x in region
    const int yb = 4 * (wv_id >> 1);                   // y base in region

    f2 acc[4][2];                                      // [yy][z-pair]
    #pragma unroll
    for (int i = 0; i < 4; ++i) { acc[i][0] = 0.0f; acc[i][1] = 0.0f; }

    {
        const unsigned char* wl = wlist[wv_id];
        #pragma unroll 2
        for (int j = 0; j < Kw; ++j) {
            const int k = wl[j];
            const float4 ya0 = *(const float4*)&wy[k][yb];
            const float4 z0  = *(const float4*)&wz[k][4 * zq];
            const float  x0v = wx[k][xi];

            const f2 cz0 = {z0.x, z0.y};
            const f2 cz1 = {z0.z, z0.w};
            const float p0 = ya0.x * x0v, p1 = ya0.y * x0v;
            const float p2 = ya0.z * x0v, p3 = ya0.w * x0v;
            acc[0][0] += p0 * cz0; acc[0][1] += p0 * cz1;
            acc[1][0] += p1 * cz0; acc[1][1] += p1 * cz1;
            acc[2][0] += p2 * cz0; acc[2][1] += p2 * cz1;
            acc[3][0] += p3 * cz0; acc[3][1] += p3 * cz1;
        }
    }

    // ---- Full-line NT stores: 4 x dwordx4 per thread, fire-and-forget. ----
    #pragma unroll
    for (int yy = 0; yy < 4; ++yy) {
        const int y = vy0 + yb + yy;
        const size_t lin = (size_t)(vx0 + xi) * (VOLD * VOLD)
                         + (size_t)y * VOLD + (size_t)(vz0 + 4 * zq);
        nfloat4 v;
        v.x = acc[yy][0].x; v.y = acc[yy][0].y;
        v.z = acc[yy][1].x; v.w = acc[yy][1].y;
        __builtin_nontemporal_store(v, (nfloat4*)&vol[lin]);
    }
}

extern "C" void kernel_launch(void* const* d_in, const int* in_sizes, int n_in,
                              void* d_out, int out_size, void* d_ws, size_t ws_size,
                              hipStream_t stream) {
    const float* centers = (const float*)d_in[0];   // (N,3)
    const float* sigmas  = (const float*)d_in[1];   // (N,)
    const float* intens  = (const float*)d_in[2];   // (N,)
    float* vol = (float*)d_out;
    const int N = in_sizes[1];                      // 4000

    splat_kernel<<<NBLK, 1024, 0, stream>>>(centers, sigmas, intens, vol, N);
}

// Round 20
// 20.508 us; speedup vs baseline: 1.0784x; 1.0784x over previous
//
#include <hip/hip_runtime.h>

#define VOLD 256
// Region = 32 x 32 x 32; grid 8 x 8 x 8 = 512 blocks, 1024 threads (16 waves).
// Per-wave 8x x 8y footprint via ballot compaction (4x4 wave grid).
// NO min-waves launch_bounds clamp (R15 lesson: VGPR clamp -> spills).
// R17 reproduction: best measured = 20.6 us.
#define CXD 32
#define CYD 32
#define CZD 32
#define NBLK 512
#define CAP 128

typedef float f2 __attribute__((ext_vector_type(2)));

__global__ __launch_bounds__(1024) void splat_kernel(
    const float* __restrict__ centers, const float* __restrict__ sigmas,
    const float* __restrict__ intens, float* __restrict__ vol, int N)
{
    const int cell = blockIdx.x;
    const int czc = cell & 7;            // 0..7
    const int cyc = (cell >> 3) & 7;     // 0..7
    const int cxc = cell >> 6;           // 0..7
    const int vx0 = cxc * CXD, vy0 = cyc * CYD, vz0 = czc * CZD;
    const int t = threadIdx.x;

    __shared__ int           lcnt;
    __shared__ float4        pc4[CAP];        // cx, cy, cz, sigma
    __shared__ float         pint[CAP];       // intensity
    __shared__ float         wx[CAP][CXD];    // intensity folded in
    __shared__ float         wy[CAP][CYD];
    __shared__ float         wz[CAP][CZD];
    __shared__ unsigned char wlist[16][CAP];  // per-wave compacted k-lists
    // ~52.6 KB -> 2 blocks/CU (LDS), 32 waves/CU if VGPR<=64

    if (t == 0) lcnt = 0;
    __syncthreads();

    // ---- Scan: 4-gaussian packs, 4 x dwordx4 loads per pack. ----
    const float axh = (float)(vx0 + CXD) + 0.5f, axl = (float)vx0 - 0.5f;
    const float ayh = (float)(vy0 + CYD) + 0.5f, ayl = (float)vy0 - 0.5f;
    const float azh = (float)(vz0 + CZD) + 0.5f, azl = (float)vz0 - 0.5f;

    const float4* c4 = (const float4*)centers;
    const float4* s4 = (const float4*)sigmas;
    const int npack = N >> 2;
    for (int i = t; i < npack; i += 1024) {
        const float4 f0  = c4[3 * i];
        const float4 f1  = c4[3 * i + 1];
        const float4 f2v = c4[3 * i + 2];
        const float4 sg4 = s4[i];
        const float gx[4] = {f0.x, f0.w, f1.z, f2v.y};
        const float gy[4] = {f0.y, f1.x, f1.w, f2v.z};
        const float gz[4] = {f0.z, f1.y, f2v.x, f2v.w};
        const float gs[4] = {sg4.x, sg4.y, sg4.z, sg4.w};
        #pragma unroll
        for (int u = 0; u < 4; ++u) {
            const float m1 = fmaxf(fmaxf(fmaf(gx[u], 255.0f, -axh),
                                         fmaf(gy[u], 255.0f, -ayh)),
                                         fmaf(gz[u], 255.0f, -azh));
            const float m2 = fmaxf(fmaxf(fmaf(-gx[u], 255.0f, axl),
                                         fmaf(-gy[u], 255.0f, ayl)),
                                         fmaf(-gz[u], 255.0f, azl));
            if (fmaxf(m1, m2) < gs[u] * 765.0f) {
                const int p = atomicAdd(&lcnt, 1);
                if (p < CAP) {
                    pc4[p]  = make_float4(gx[u], gy[u], gz[u], gs[u]);
                    pint[p] = intens[4 * i + u];
                }
            }
        }
    }
    for (int g = (npack << 2) + t; g < N; g += 1024) {   // tail, robustness
        const float cx = centers[3 * g], cy = centers[3 * g + 1], cz = centers[3 * g + 2];
        const float sg = sigmas[g];
        const float m1 = fmaxf(fmaxf(fmaf(cx, 255.0f, -axh), fmaf(cy, 255.0f, -ayh)),
                               fmaf(cz, 255.0f, -azh));
        const float m2 = fmaxf(fmaxf(fmaf(-cx, 255.0f, axl), fmaf(-cy, 255.0f, ayl)),
                               fmaf(-cz, 255.0f, azl));
        if (fmaxf(m1, m2) < sg * 765.0f) {
            const int p = atomicAdd(&lcnt, 1);
            if (p < CAP) { pc4[p] = make_float4(cx, cy, cz, sg); pint[p] = intens[g]; }
        }
    }
    __syncthreads();
    const int K = min(lcnt, CAP);

    // ---- Weights (float-domain validity == reference's floor/int logic). ----
    for (int i = t; i < K * CXD; i += 1024) {
        const int g = i >> 5, o = i & 31;
        const float4 p = pc4[g];
        const float cn = p.x, sig = p.w;
        const float cv = cn * 255.0f, cut = 3.0f * sig * 255.0f;
        const float fi = (float)(vx0 + o);
        float wv = 0.0f;
        if ((fi + 1.0f > cv - cut) && (fi <= fminf(cv + cut, 255.0f))) {
            const float d = fi * (1.0f / 255.0f) - cn;
            wv = __expf(-d * d * (0.5f / (sig * sig))) * pint[g];
        }
        wx[g][o] = wv;
    }
    for (int i = t; i < K * CYD; i += 1024) {
        const int g = i >> 5, o = i & 31;
        const float4 p = pc4[g];
        const float cn = p.y, sig = p.w;
        const float cv = cn * 255.0f, cut = 3.0f * sig * 255.0f;
        const float fi = (float)(vy0 + o);
        float wv = 0.0f;
        if ((fi + 1.0f > cv - cut) && (fi <= fminf(cv + cut, 255.0f))) {
            const float d = fi * (1.0f / 255.0f) - cn;
            wv = __expf(-d * d * (0.5f / (sig * sig)));
        }
        wy[g][o] = wv;
    }
    for (int i = t; i < K * CZD; i += 1024) {
        const int g = i >> 5, o = i & 31;
        const float4 p = pc4[g];
        const float cn = p.z, sig = p.w;
        const float cv = cn * 255.0f, cut = 3.0f * sig * 255.0f;
        const float fi = (float)(vz0 + o);
        float wv = 0.0f;
        if ((fi + 1.0f > cv - cut) && (fi <= fminf(cv + cut, 255.0f))) {
            const float d = fi * (1.0f / 255.0f) - cn;
            wv = __expf(-d * d * (0.5f / (sig * sig)));
        }
        wz[g][o] = wv;
    }
    __syncthreads();

    // ---- Per-wave list compaction: this wave's 8x x 8y footprint. ----
    const int wv_id = t >> 6;            // wave 0..15 (4x4 grid)
    const int lane  = t & 63;
    const float xw0 = (float)(vx0 + 8 * (wv_id & 3));   // x-window [xw0, xw0+8)
    const float yw0 = (float)(vy0 + 8 * (wv_id >> 2));  // y-window [yw0, yw0+8)

    int Kw = 0;
    for (int j0 = 0; j0 < K; j0 += 64) {
        const int j = j0 + lane;
        bool rel = false;
        if (j < K) {
            const float4 p = pc4[j];
            const float cvx = p.x * 255.0f, cvy = p.y * 255.0f;
            const float cut = p.w * 765.0f;
            // loose (+1 voxel) overlap vs weight support: false POSITIVES only
            rel = (cvx + cut >= xw0 - 1.0f) && (cvx - cut <= xw0 + 9.0f) &&
                  (cvy + cut >= yw0 - 1.0f) && (cvy - cut <= yw0 + 9.0f);
        }
        const unsigned long long m = __ballot(rel);
        if (rel) {
            const int pos = Kw + __popcll(m & ((1ull << lane) - 1ull));
            wlist[wv_id][pos] = (unsigned char)j;
        }
        Kw += __popcll(m);
    }
    // wlist[wv_id] written & read by the same wave only -> no barrier needed.

    // ---- Accumulate over compacted list: simple body, TLP hides LDS latency. -
    const int zq = t & 7;                              // z = 4*zq .. 4*zq+3
    const int xi = 8 * (wv_id & 3) + ((t >> 3) & 7);   // x in region
    const int yb = 8 * (wv_id >> 2);                   // y base in region

    f2 acc[8][2];                                      // [yy][z-pair]
    #pragma unroll
    for (int i = 0; i < 8; ++i) { acc[i][0] = 0.0f; acc[i][1] = 0.0f; }

    {
        const unsigned char* wl = wlist[wv_id];
        #pragma unroll 2
        for (int j = 0; j < Kw; ++j) {
            const int k = wl[j];
            const float4 ya0 = *(const float4*)&wy[k][yb];
            const float4 yb0 = *(const float4*)&wy[k][yb + 4];
            const float4 z0  = *(const float4*)&wz[k][4 * zq];
            const float  x0v = wx[k][xi];

            const f2 cz0 = {z0.x, z0.y};
            const f2 cz1 = {z0.z, z0.w};
            const float p0 = ya0.x * x0v, p1 = ya0.y * x0v;
            const float p2 = ya0.z * x0v, p3 = ya0.w * x0v;
            const float p4 = yb0.x * x0v, p5 = yb0.y * x0v;
            const float p6 = yb0.z * x0v, p7 = yb0.w * x0v;
            acc[0][0] += p0 * cz0; acc[0][1] += p0 * cz1;
            acc[1][0] += p1 * cz0; acc[1][1] += p1 * cz1;
            acc[2][0] += p2 * cz0; acc[2][1] += p2 * cz1;
            acc[3][0] += p3 * cz0; acc[3][1] += p3 * cz1;
            acc[4][0] += p4 * cz0; acc[4][1] += p4 * cz1;
            acc[5][0] += p5 * cz0; acc[5][1] += p5 * cz1;
            acc[6][0] += p6 * cz0; acc[6][1] += p6 * cz1;
            acc[7][0] += p7 * cz0; acc[7][1] += p7 * cz1;
        }
    }

    // ---- Full-line plain stores: 8 x dwordx4 per thread. ----
    #pragma unroll
    for (int yy = 0; yy < 8; ++yy) {
        const int y = vy0 + yb + yy;
        const size_t lin = (size_t)(vx0 + xi) * (VOLD * VOLD)
                         + (size_t)y * VOLD + (size_t)(vz0 + 4 * zq);
        float4 v;
        v.x = acc[yy][0].x; v.y = acc[yy][0].y;
        v.z = acc[yy][1].x; v.w = acc[yy][1].y;
        *(float4*)&vol[lin] = v;
    }
}

extern "C" void kernel_launch(void* const* d_in, const int* in_sizes, int n_in,
                              void* d_out, int out_size, void* d_ws, size_t ws_size,
                              hipStream_t stream) {
    const float* centers = (const float*)d_in[0];   // (N,3)
    const float* sigmas  = (const float*)d_in[1];   // (N,)
    const float* intens  = (const float*)d_in[2];   // (N,)
    float* vol = (float*)d_out;
    const int N = in_sizes[1];                      // 4000

    splat_kernel<<<NBLK, 1024, 0, stream>>>(centers, sigmas, intens, vol, N);
}